// Round 14
// baseline (144.759 us; speedup 1.0000x reference)
//
#include <hip/hip_runtime.h>
#include <hip/hip_bf16.h>

#define Dx 300
#define Mx 1024

// float-offsets into ws
#define OFF_REP    0
#define OFF_DEP    307200      // holds exd = exp(0.4*(dep+b1))
#define OFF_HEAD   614400
#define OFF_ATTN   921600
// ushort arrays at U = (ushort*)(ws + 1228800): zero-padded [1024][320]
#define U_BASE     1228800
#define REPB       0
#define ATB        327680

typedef __attribute__((ext_vector_type(8))) short short8;
typedef __attribute__((ext_vector_type(4))) float f32x4;

union S8 { unsigned int u[4]; unsigned short s[8]; short8 v; };

__device__ __forceinline__ float bf2f(unsigned short u) {
    union { unsigned int i; float f; } v; v.i = ((unsigned int)u) << 16; return v.f;
}
__device__ __forceinline__ unsigned short f2bf(float x) {   // round-half-up
    union { float f; unsigned int i; } u; u.f = x;
    return (unsigned short)((u.i + 0x8000u) >> 16);
}
__device__ __forceinline__ int detect_bf16(const void* w) {
    const unsigned short* u = (const unsigned short*)w;
    int ok = 1;
    #pragma unroll
    for (int t = 0; t < 64; ++t) { float v = bf2f(u[t]); ok &= (fabsf(v) < 1.0f) ? 1 : 0; }
    return ok;
}
__device__ __forceinline__ float ldf(const void* p, int idx, int isbf) {
    return isbf ? bf2f(((const unsigned short*)p)[idx]) : ((const float*)p)[idx];
}

__device__ __forceinline__ void load8f(const float* rowp, int kb, int kmax,
                                       int valid, float* x) {
    if (valid && kb + 8 <= kmax) {
        float4 a = *(const float4*)(rowp + kb);
        float4 b = *(const float4*)(rowp + kb + 4);
        x[0]=a.x; x[1]=a.y; x[2]=a.z; x[3]=a.w;
        x[4]=b.x; x[5]=b.y; x[6]=b.z; x[7]=b.w;
    } else {
        #pragma unroll
        for (int j = 0; j < 8; ++j) {
            int k = kb + j;
            x[j] = (valid && k < kmax) ? rowp[k] : 0.f;
        }
    }
}
__device__ __forceinline__ short8 pack8(const float* x) {
    S8 H;
    #pragma unroll
    for (int p = 0; p < 4; ++p) {
        union { float f; unsigned int i; } a, b;
        a.f = x[2*p]; b.f = x[2*p+1];
        H.u[p] = ((a.i + 0x8000u) >> 16) | ((b.i + 0x8000u) & 0xFFFF0000u);
    }
    return H.v;
}
__device__ __forceinline__ short8 load8bf(const unsigned short* rowp, int kb,
                                          int kmax, int valid) {
    S8 R;
    if (valid && kb + 8 <= kmax) {
        ushort4 a = *(const ushort4*)(rowp + kb);
        ushort4 b = *(const ushort4*)(rowp + kb + 4);
        R.s[0]=a.x; R.s[1]=a.y; R.s[2]=a.z; R.s[3]=a.w;
        R.s[4]=b.x; R.s[5]=b.y; R.s[6]=b.z; R.s[7]=b.w;
    } else {
        #pragma unroll
        for (int j = 0; j < 8; ++j) {
            int k = kb + j;
            R.s[j] = (valid && k < kmax) ? rowp[k] : (unsigned short)0;
        }
    }
    return R.v;
}
__device__ __forceinline__ short8 loadB(const void* W, int row, int kb, int isbf,
                                        int valid) {
    if (isbf) return load8bf((const unsigned short*)W + row * 300, kb, 300, valid);
    float t[8];
    load8f((const float*)W + row * 300, kb, 300, valid, t);
    return pack8(t);
}

// ---------------------------------------------------------------------------
// k_head: fused rep + dep/head, NO duplication of per-wave work.
// grid 128 = 64mt x 2 N-halves, 640 thr (10 waves).
// Phase A: 19 rep subtiles over 10 waves (<=2 each); rep -> LDS bf16
//          (+ fp32/bf16 global stores by half 0 only).
// Phase B: this half's 20 of 40 dep/head subtiles, A-frags from LDS.
// ---------------------------------------------------------------------------
__global__ __launch_bounds__(640) void k_head(
        const void* __restrict__ Xv, const void* __restrict__ Wfc,
        const void* __restrict__ bfc, const void* __restrict__ W1,
        const void* __restrict__ W2,  const void* __restrict__ b1,
        float* __restrict__ ws) {
    __shared__ __align__(16) unsigned short repL[16][328];
    __shared__ int s_isbf;
    const int tid = threadIdx.x;
    if (tid == 0) s_isbf = detect_bf16(Wfc);
    if (tid < 448) {                         // zero LDS pad cols 300..327
        int m = tid / 28, c = 300 + tid % 28;
        repL[m][c] = 0;
    }
    __syncthreads();
    const int isbf = s_isbf;
    const int w = tid >> 6, l = tid & 63;
    const int lm = l & 15, koff = (l >> 4) * 8;
    const int mt = blockIdx.x >> 1, half = blockIdx.x & 1;
    const int m0 = mt * 16;
    unsigned short* U = (unsigned short*)(ws + U_BASE);

    // ---- Phase A: rep tile (16x300) ----
    short8 xa[10];
    if (isbf) {
        const unsigned short* Xp = (const unsigned short*)Xv + (m0 + lm) * 300;
        #pragma unroll
        for (int ks = 0; ks < 10; ++ks) xa[ks] = load8bf(Xp, ks*32 + koff, 300, 1);
    } else {
        const float* Xp = (const float*)Xv + (m0 + lm) * 300;
        #pragma unroll
        for (int ks = 0; ks < 10; ++ks) {
            float t[8]; load8f(Xp, ks*32 + koff, 300, 1, t);
            xa[ks] = pack8(t);
        }
    }
    #pragma unroll
    for (int s = 0; s < 2; ++s) {
        const int ns = w + s * 10;
        if (ns < 19) {
            const int nb = ns * 16 + lm;
            const int bval = nb < 300;
            const int ncl = bval ? nb : 0;
            f32x4 acc = {0.f, 0.f, 0.f, 0.f};
            #pragma unroll
            for (int ks = 0; ks < 10; ++ks) {
                short8 b = loadB(Wfc, ncl, ks*32 + koff, isbf, bval);
                acc = __builtin_amdgcn_mfma_f32_16x16x32_bf16(xa[ks], b, acc, 0, 0, 0);
            }
            if (bval) {
                float bb = ldf(bfc, nb, isbf);
                #pragma unroll
                for (int r = 0; r < 4; ++r) {
                    int ml = (l >> 4) * 4 + r;
                    float v = acc[r] + bb;
                    v = v > 0.f ? v : (__expf(v) - 1.f);
                    unsigned short hv = f2bf(v);
                    repL[ml][nb] = hv;
                    if (half == 0) {
                        ws[OFF_REP + (m0 + ml) * 300 + nb] = v;
                        U[REPB + (m0 + ml) * 320 + nb] = hv;
                    }
                }
            }
        }
    }
    if (half == 0 && tid < 320) {            // zero repB global pad cols 300..319
        int m = tid / 20, c = 300 + tid % 20;
        U[REPB + (m0 + m) * 320 + c] = 0;
    }
    __syncthreads();

    // ---- Phase B: dep/head, A from LDS ----
    short8 ra[10];
    #pragma unroll
    for (int ks = 0; ks < 10; ++ks)
        ra[ks] = *(const short8*)&repL[lm][ks*32 + koff];
    #pragma unroll
    for (int s = 0; s < 2; ++s) {
        const int ns2 = w + s * 10 + half * 20;      // 0..39
        const int ng = ns2 * 16 + lm;                // 0..639
        const int wsel = ng < 320;
        const int wrow = wsel ? ng : ng - 320;
        const int bval = wrow < 300;
        const int wcl = bval ? wrow : 0;
        const void* Wp = wsel ? W1 : W2;
        f32x4 acc = {0.f, 0.f, 0.f, 0.f};
        #pragma unroll
        for (int ks = 0; ks < 10; ++ks) {
            short8 b = loadB(Wp, wcl, ks*32 + koff, isbf, bval);
            acc = __builtin_amdgcn_mfma_f32_16x16x32_bf16(ra[ks], b, acc, 0, 0, 0);
        }
        if (ng < 300) {
            float bb = ldf(b1, ng, isbf);
            #pragma unroll
            for (int r = 0; r < 4; ++r) {
                int mg = m0 + (l >> 4) * 4 + r;
                ws[OFF_DEP + mg * 300 + ng] = __expf(0.4f * (acc[r] + bb));
            }
        } else if (ng >= 320 && ng < 620) {
            #pragma unroll
            for (int r = 0; r < 4; ++r) {
                int mg = m0 + (l >> 4) * 4 + r;
                ws[OFF_HEAD + mg * 300 + (ng - 320)] = acc[r];
            }
        }
    }
}

// ---------------------------------------------------------------------------
// k_attn: single-pass branchless, fixed shift m=C, consumes exd.
// Epilogue also emits padded bf16 atB. grid 512, 320 thr (R13-proven).
// ---------------------------------------------------------------------------
__global__ __launch_bounds__(320) void k_attn(
        float* __restrict__ ws, const int* __restrict__ mask) {
    const float* exd  = ws + OFF_DEP;
    const float* head = ws + OFF_HEAD;
    const float* rep  = ws + OFF_REP;
    unsigned short* U = (unsigned short*)(ws + U_BASE);
    __shared__ float mkf[256];
    const int blk = blockIdx.x;
    const int b = blk >> 7;
    const int tile = blk & 127;
    const int u = tile >> 1;
    const int i0 = (tile & 1) ? (254 - 2 * u) : (2 * u);
    const int tid = threadIdx.x;
    if (tid < 256) mkf[tid] = (float)mask[b * 256 + tid];
    __syncthreads();
    const int d = tid;
    const int base = b * 256;
    if (d >= 300) {
        U[ATB + (base + i0) * 320 + d] = 0;
        U[ATB + (base + i0 + 1) * 320 + d] = 0;
        return;
    }

    const float hv0 = head[(base + i0) * Dx + d];
    const float hv1 = head[(base + i0 + 1) * Dx + d];
    const float pw0 = __expf(0.4f * hv0);
    const float pw1 = __expf(0.4f * hv1);

    float s0 = 0.f, r0 = 0.f, s1 = 0.f, r1 = 0.f;
    {
        const int j = i0 + 1;
        float ex = exd[(base + j) * Dx + d];
        float rv = rep[(base + j) * Dx + d];
        float mk = mkf[j];
        float u0 = fmaf(ex, pw0, 1.0f);
        float e0 = __expf(-10.0f * __builtin_amdgcn_rcpf(u0));
        float em0 = e0 * mk;
        s0 += em0; r0 = fmaf(em0, rv, r0);
    }
    const float* ep = exd + base * Dx + d;
    const float* rp = rep + base * Dx + d;
    #pragma unroll 4
    for (int j = i0 + 2; j < 256; ++j) {
        float ex = ep[j * Dx];
        float rv = rp[j * Dx];
        float mk = mkf[j];
        float u0 = fmaf(ex, pw0, 1.0f);
        float u1 = fmaf(ex, pw1, 1.0f);
        float e0 = __expf(-10.0f * __builtin_amdgcn_rcpf(u0));
        float e1 = __expf(-10.0f * __builtin_amdgcn_rcpf(u1));
        float em0 = e0 * mk;
        float em1 = e1 * mk;
        s0 += em0; r0 = fmaf(em0, rv, r0);
        s1 += em1; r1 = fmaf(em1, rv, r1);
    }
    const float den0 = s0 + (s0 == 0.f ? 1.f : 0.f) + 1e-20f;
    const float den1 = s1 + (s1 == 0.f ? 1.f : 0.f) + 1e-20f;
    const float a0 = r0 / den0, a1 = r1 / den1;
    ws[OFF_ATTN + (base + i0) * Dx + d]     = a0;
    ws[OFF_ATTN + (base + i0 + 1) * Dx + d] = a1;
    U[ATB + (base + i0) * 320 + d]     = f2bf(a0);
    U[ATB + (base + i0 + 1) * 320 + d] = f2bf(a1);
}

// ---------------------------------------------------------------------------
// k_mm3: gate = sigmoid(rep@Wf1^T + attn@Wf2^T + bf); blend; mask; store.
// A operands pre-packed (repB/atB). grid 320 = 64mt x 5nt (R13-proven).
// ---------------------------------------------------------------------------
__global__ __launch_bounds__(256) void k_mm3(
        const void* __restrict__ Wf1, const void* __restrict__ Wf2,
        const void* __restrict__ bfv, const int* __restrict__ mask,
        float* __restrict__ ws, void* __restrict__ outv) {
    __shared__ int s_isbf;
    if (threadIdx.x == 0) s_isbf = detect_bf16(Wf1);
    __syncthreads();
    const int isbf = s_isbf;
    const int tid = threadIdx.x, w = tid >> 6, l = tid & 63;
    const int mt = blockIdx.x / 5, nt = blockIdx.x % 5;
    const int m0 = mt * 16, lm = l & 15, koff = (l >> 4) * 8;
    const int nrow = nt * 64 + w * 16 + lm;
    const int bval = nrow < 300;
    const int ncl = bval ? nrow : 0;
    const unsigned short* U = (const unsigned short*)(ws + U_BASE);
    const unsigned short* a1p = U + REPB + (m0 + lm) * 320 + koff;
    const unsigned short* a2p = U + ATB  + (m0 + lm) * 320 + koff;
    f32x4 acc = {0.f, 0.f, 0.f, 0.f};
    #pragma unroll
    for (int ks = 0; ks < 10; ++ks) {
        short8 a = *(const short8*)(a1p + ks * 32);
        short8 b = loadB(Wf1, ncl, ks*32 + koff, isbf, bval);
        acc = __builtin_amdgcn_mfma_f32_16x16x32_bf16(a, b, acc, 0, 0, 0);
    }
    #pragma unroll
    for (int ks = 0; ks < 10; ++ks) {
        short8 a = *(const short8*)(a2p + ks * 32);
        short8 b = loadB(Wf2, ncl, ks*32 + koff, isbf, bval);
        acc = __builtin_amdgcn_mfma_f32_16x16x32_bf16(a, b, acc, 0, 0, 0);
    }
    if (bval) {
        float bb = ldf(bfv, nrow, isbf);
        #pragma unroll
        for (int r = 0; r < 4; ++r) {
            int mg = m0 + (l >> 4) * 4 + r;
            float gp = acc[r] + bb;
            float gate = 1.0f / (1.0f + __expf(-gp));
            float rv = ws[OFF_REP  + mg * 300 + nrow];
            float av = ws[OFF_ATTN + mg * 300 + nrow];
            float res = (gate * rv + (1.0f - gate) * av) * (float)mask[mg];
            if (isbf) ((__hip_bfloat16*)outv)[mg * 300 + nrow] = __float2bfloat16(res);
            else      ((float*)outv)[mg * 300 + nrow] = res;
        }
    }
}

extern "C" void kernel_launch(void* const* d_in, const int* in_sizes, int n_in,
                              void* d_out, int out_size, void* d_ws, size_t ws_size,
                              hipStream_t stream) {
    const void* X   = d_in[0];
    const int*  msk = (const int*)d_in[1];
    const void* Wfc = d_in[2];
    const void* bfc = d_in[3];
    const void* W1  = d_in[4];
    const void* W2  = d_in[5];
    const void* b1  = d_in[6];
    const void* Wf1 = d_in[7];
    const void* Wf2 = d_in[8];
    const void* bfv = d_in[9];
    float* ws = (float*)d_ws;

    hipLaunchKernelGGL(k_head, dim3(128), dim3(640), 0, stream,
                       X, Wfc, bfc, W1, W2, b1, ws);
    hipLaunchKernelGGL(k_attn, dim3(512), dim3(320), 0, stream, ws, msk);
    hipLaunchKernelGGL(k_mm3,  dim3(320), dim3(256), 0, stream,
                       Wf1, Wf2, bfv, msk, ws, d_out);
}

// Round 15
// 125.491 us; speedup vs baseline: 1.1535x; 1.1535x over previous
//
#include <hip/hip_runtime.h>
#include <hip/hip_bf16.h>

#define Dx 300
#define Mx 1024

// float-offsets into ws
#define OFF_REP    0
#define OFF_DEP    307200      // holds exd = exp(0.4*(dep+b1))
#define OFF_HEAD   614400
#define OFF_ATTN   921600
// ushort arrays at U = (ushort*)(ws + 1228800): zero-padded [1024][320]
#define U_BASE     1228800
#define REPB       0
#define ATB        327680

typedef __attribute__((ext_vector_type(8))) short short8;
typedef __attribute__((ext_vector_type(4))) float f32x4;

union S8 { unsigned int u[4]; unsigned short s[8]; short8 v; };

__device__ __forceinline__ float bf2f(unsigned short u) {
    union { unsigned int i; float f; } v; v.i = ((unsigned int)u) << 16; return v.f;
}
__device__ __forceinline__ unsigned short f2bf(float x) {   // round-half-up
    union { float f; unsigned int i; } u; u.f = x;
    return (unsigned short)((u.i + 0x8000u) >> 16);
}
__device__ __forceinline__ int detect_bf16(const void* w) {
    const unsigned short* u = (const unsigned short*)w;
    int ok = 1;
    #pragma unroll
    for (int t = 0; t < 64; ++t) { float v = bf2f(u[t]); ok &= (fabsf(v) < 1.0f) ? 1 : 0; }
    return ok;
}
__device__ __forceinline__ float ldf(const void* p, int idx, int isbf) {
    return isbf ? bf2f(((const unsigned short*)p)[idx]) : ((const float*)p)[idx];
}

__device__ __forceinline__ void load8f(const float* rowp, int kb, int kmax,
                                       int valid, float* x) {
    if (valid && kb + 8 <= kmax) {
        float4 a = *(const float4*)(rowp + kb);
        float4 b = *(const float4*)(rowp + kb + 4);
        x[0]=a.x; x[1]=a.y; x[2]=a.z; x[3]=a.w;
        x[4]=b.x; x[5]=b.y; x[6]=b.z; x[7]=b.w;
    } else {
        #pragma unroll
        for (int j = 0; j < 8; ++j) {
            int k = kb + j;
            x[j] = (valid && k < kmax) ? rowp[k] : 0.f;
        }
    }
}
__device__ __forceinline__ short8 pack8(const float* x) {
    S8 H;
    #pragma unroll
    for (int p = 0; p < 4; ++p) {
        union { float f; unsigned int i; } a, b;
        a.f = x[2*p]; b.f = x[2*p+1];
        H.u[p] = ((a.i + 0x8000u) >> 16) | ((b.i + 0x8000u) & 0xFFFF0000u);
    }
    return H.v;
}
__device__ __forceinline__ short8 load8bf(const unsigned short* rowp, int kb,
                                          int kmax, int valid) {
    S8 R;
    if (valid && kb + 8 <= kmax) {
        ushort4 a = *(const ushort4*)(rowp + kb);
        ushort4 b = *(const ushort4*)(rowp + kb + 4);
        R.s[0]=a.x; R.s[1]=a.y; R.s[2]=a.z; R.s[3]=a.w;
        R.s[4]=b.x; R.s[5]=b.y; R.s[6]=b.z; R.s[7]=b.w;
    } else {
        #pragma unroll
        for (int j = 0; j < 8; ++j) {
            int k = kb + j;
            R.s[j] = (valid && k < kmax) ? rowp[k] : (unsigned short)0;
        }
    }
    return R.v;
}
__device__ __forceinline__ short8 loadB(const void* W, int row, int kb, int isbf,
                                        int valid) {
    if (isbf) return load8bf((const unsigned short*)W + row * 300, kb, 300, valid);
    float t[8];
    load8f((const float*)W + row * 300, kb, 300, valid, t);
    return pack8(t);
}

// ---------------------------------------------------------------------------
// k_mm1: rep = elu(X @ Wfc^T + bfc). grid 320 = 64mt x 5nt (R13-proven).
// ---------------------------------------------------------------------------
__global__ __launch_bounds__(256) void k_mm1(
        const void* __restrict__ Xv, const void* __restrict__ Wfc,
        const void* __restrict__ bfc, float* __restrict__ ws) {
    __shared__ int s_isbf;
    if (threadIdx.x == 0) s_isbf = detect_bf16(Wfc);
    __syncthreads();
    const int isbf = s_isbf;
    const int tid = threadIdx.x, w = tid >> 6, l = tid & 63;
    const int mt = blockIdx.x / 5, nt = blockIdx.x % 5;
    const int m0 = mt * 16, lm = l & 15, koff = (l >> 4) * 8;
    const int nrow = nt * 64 + w * 16 + lm;          // 0..319
    const int bval = nrow < 300;
    const int ncl = bval ? nrow : 0;
    unsigned short* U = (unsigned short*)(ws + U_BASE);
    f32x4 acc = {0.f, 0.f, 0.f, 0.f};
    if (isbf) {
        const unsigned short* Xp = (const unsigned short*)Xv + (m0 + lm) * 300;
        #pragma unroll
        for (int ks = 0; ks < 10; ++ks) {
            short8 a = load8bf(Xp, ks*32 + koff, 300, 1);
            short8 b = loadB(Wfc, ncl, ks*32 + koff, 1, bval);
            acc = __builtin_amdgcn_mfma_f32_16x16x32_bf16(a, b, acc, 0, 0, 0);
        }
    } else {
        const float* Xp = (const float*)Xv + (m0 + lm) * 300;
        #pragma unroll
        for (int ks = 0; ks < 10; ++ks) {
            float t[8]; load8f(Xp, ks*32 + koff, 300, 1, t);
            short8 a = pack8(t);
            short8 b = loadB(Wfc, ncl, ks*32 + koff, 0, bval);
            acc = __builtin_amdgcn_mfma_f32_16x16x32_bf16(a, b, acc, 0, 0, 0);
        }
    }
    if (bval) {
        float bb = ldf(bfc, nrow, isbf);
        #pragma unroll
        for (int r = 0; r < 4; ++r) {
            int mg = m0 + (l >> 4) * 4 + r;
            float v = acc[r] + bb;
            v = v > 0.f ? v : (__expf(v) - 1.f);
            ws[OFF_REP + mg * 300 + nrow] = v;
            U[REPB + mg * 320 + nrow] = f2bf(v);
        }
    } else {
        #pragma unroll
        for (int r = 0; r < 4; ++r) {
            int mg = m0 + (l >> 4) * 4 + r;
            U[REPB + mg * 320 + nrow] = 0;
        }
    }
}

// ---------------------------------------------------------------------------
// k_mm2: dep/head from repB (pre-packed A). grid 640 = 64mt x 10nt.
// dep epilogue stores exd = exp(0.4*(dep+b1)). (R13-proven)
// ---------------------------------------------------------------------------
__global__ __launch_bounds__(256) void k_mm2(
        const void* __restrict__ W1, const void* __restrict__ W2,
        const void* __restrict__ b1, float* __restrict__ ws) {
    __shared__ int s_isbf;
    if (threadIdx.x == 0) s_isbf = detect_bf16(W1);
    __syncthreads();
    const int isbf = s_isbf;
    const int tid = threadIdx.x, w = tid >> 6, l = tid & 63;
    const int mt = blockIdx.x / 10, nt = blockIdx.x % 10;
    const int m0 = mt * 16, lm = l & 15, koff = (l >> 4) * 8;
    const int ng = nt * 64 + w * 16 + lm;            // 0..639
    const int wsel = ng < 320;
    const int wrow = wsel ? ng : ng - 320;
    const int bval = wrow < 300;
    const int wcl = bval ? wrow : 0;
    const void* Wp = wsel ? W1 : W2;
    const unsigned short* U = (const unsigned short*)(ws + U_BASE);
    const unsigned short* ap = U + REPB + (m0 + lm) * 320 + koff;
    f32x4 acc = {0.f, 0.f, 0.f, 0.f};
    #pragma unroll
    for (int ks = 0; ks < 10; ++ks) {
        short8 a = *(const short8*)(ap + ks * 32);
        short8 b = loadB(Wp, wcl, ks*32 + koff, isbf, bval);
        acc = __builtin_amdgcn_mfma_f32_16x16x32_bf16(a, b, acc, 0, 0, 0);
    }
    if (ng < 300) {
        float bb = ldf(b1, ng, isbf);
        #pragma unroll
        for (int r = 0; r < 4; ++r) {
            int mg = m0 + (l >> 4) * 4 + r;
            ws[OFF_DEP + mg * 300 + ng] = __expf(0.4f * (acc[r] + bb));
        }
    } else if (ng >= 320 && ng < 620) {
        #pragma unroll
        for (int r = 0; r < 4; ++r) {
            int mg = m0 + (l >> 4) * 4 + r;
            ws[OFF_HEAD + mg * 300 + (ng - 320)] = acc[r];
        }
    }
}

// ---------------------------------------------------------------------------
// k_attn: single-pass, fixed shift m=C, consumes exd. NEW: valid-j indices
// compacted once per block via wave-0 ballot (mask density ~0.5 -> half the
// inner-loop iterations, no mask multiply). grid 512, 320 thr.
// ---------------------------------------------------------------------------
__global__ __launch_bounds__(320) void k_attn(
        float* __restrict__ ws, const int* __restrict__ mask) {
    const float* exd  = ws + OFF_DEP;
    const float* head = ws + OFF_HEAD;
    const float* rep  = ws + OFF_REP;
    unsigned short* U = (unsigned short*)(ws + U_BASE);
    __shared__ unsigned short vlist[256];
    __shared__ int s_cnt, s_st0, s_st1;
    const int blk = blockIdx.x;
    const int b = blk >> 7;
    const int tile = blk & 127;
    const int uu = tile >> 1;
    const int i0 = (tile & 1) ? (254 - 2 * uu) : (2 * uu);
    const int tid = threadIdx.x;

    if (tid < 64) {     // wave-0 ballot compaction of valid j + start indices
        int basec = 0, st0 = 0, st1 = 0;
        #pragma unroll
        for (int c = 0; c < 4; ++c) {
            const int j = c * 64 + tid;
            const int mv = mask[b * 256 + j] != 0;
            unsigned long long bal = __ballot(mv);
            int pos = basec + __popcll(bal & ((1ull << tid) - 1ull));
            if (mv) vlist[pos] = (unsigned short)j;
            if (tid == 0) {
                int lim0 = i0 - c * 64;          // count valid j <= i0
                if (lim0 >= 0)
                    st0 += __popcll(bal & (lim0 >= 63 ? ~0ull : ((2ull << lim0) - 1ull)));
                int lim1 = i0 + 1 - c * 64;      // count valid j <= i0+1
                if (lim1 >= 0)
                    st1 += __popcll(bal & (lim1 >= 63 ? ~0ull : ((2ull << lim1) - 1ull)));
            }
            basec += __popcll(bal);
        }
        if (tid == 0) { s_cnt = basec; s_st0 = st0; s_st1 = st1; }
    }
    __syncthreads();
    const int d = tid;
    const int base = b * 256;
    if (d >= 300) {                                  // zero k-pad of atB
        U[ATB + (base + i0) * 320 + d] = 0;
        U[ATB + (base + i0 + 1) * 320 + d] = 0;
        return;
    }
    const int cnt = s_cnt, st0 = s_st0, st1 = s_st1;

    const float hv0 = head[(base + i0) * Dx + d];
    const float hv1 = head[(base + i0 + 1) * Dx + d];
    const float pw0 = __expf(0.4f * hv0);
    const float pw1 = __expf(0.4f * hv1);

    const float* ep = exd + base * Dx + d;
    const float* rp = rep + base * Dx + d;
    float s0 = 0.f, r0 = 0.f, s1 = 0.f, r1 = 0.f;
    if (st1 > st0) {                  // j = i0+1 valid: row i0 only
        const int j = vlist[st0];
        float ex = ep[j * Dx];
        float rv = rp[j * Dx];
        float u0 = fmaf(ex, pw0, 1.0f);
        float e0 = __expf(-10.0f * __builtin_amdgcn_rcpf(u0));
        s0 += e0; r0 = fmaf(e0, rv, r0);
    }
    #pragma unroll 4
    for (int t = st1; t < cnt; ++t) {
        const int j = vlist[t];
        float ex = ep[j * Dx];
        float rv = rp[j * Dx];
        float u0 = fmaf(ex, pw0, 1.0f);
        float u1 = fmaf(ex, pw1, 1.0f);
        float e0 = __expf(-10.0f * __builtin_amdgcn_rcpf(u0));
        float e1 = __expf(-10.0f * __builtin_amdgcn_rcpf(u1));
        s0 += e0; r0 = fmaf(e0, rv, r0);
        s1 += e1; r1 = fmaf(e1, rv, r1);
    }
    const float den0 = s0 + (s0 == 0.f ? 1.f : 0.f) + 1e-20f;
    const float den1 = s1 + (s1 == 0.f ? 1.f : 0.f) + 1e-20f;
    const float a0 = r0 / den0, a1 = r1 / den1;
    ws[OFF_ATTN + (base + i0) * Dx + d]     = a0;
    ws[OFF_ATTN + (base + i0 + 1) * Dx + d] = a1;
    U[ATB + (base + i0) * 320 + d]     = f2bf(a0);
    U[ATB + (base + i0 + 1) * 320 + d] = f2bf(a1);
}

// ---------------------------------------------------------------------------
// k_mm3: gate = sigmoid(rep@Wf1^T + attn@Wf2^T + bf); blend; mask; store.
// A operands pre-packed (repB/atB). grid 320 = 64mt x 5nt (R13-proven).
// ---------------------------------------------------------------------------
__global__ __launch_bounds__(256) void k_mm3(
        const void* __restrict__ Wf1, const void* __restrict__ Wf2,
        const void* __restrict__ bfv, const int* __restrict__ mask,
        float* __restrict__ ws, void* __restrict__ outv) {
    __shared__ int s_isbf;
    if (threadIdx.x == 0) s_isbf = detect_bf16(Wf1);
    __syncthreads();
    const int isbf = s_isbf;
    const int tid = threadIdx.x, w = tid >> 6, l = tid & 63;
    const int mt = blockIdx.x / 5, nt = blockIdx.x % 5;
    const int m0 = mt * 16, lm = l & 15, koff = (l >> 4) * 8;
    const int nrow = nt * 64 + w * 16 + lm;
    const int bval = nrow < 300;
    const int ncl = bval ? nrow : 0;
    const unsigned short* U = (const unsigned short*)(ws + U_BASE);
    const unsigned short* a1p = U + REPB + (m0 + lm) * 320 + koff;
    const unsigned short* a2p = U + ATB  + (m0 + lm) * 320 + koff;
    f32x4 acc = {0.f, 0.f, 0.f, 0.f};
    #pragma unroll
    for (int ks = 0; ks < 10; ++ks) {
        short8 a = *(const short8*)(a1p + ks * 32);
        short8 b = loadB(Wf1, ncl, ks*32 + koff, isbf, bval);
        acc = __builtin_amdgcn_mfma_f32_16x16x32_bf16(a, b, acc, 0, 0, 0);
    }
    #pragma unroll
    for (int ks = 0; ks < 10; ++ks) {
        short8 a = *(const short8*)(a2p + ks * 32);
        short8 b = loadB(Wf2, ncl, ks*32 + koff, isbf, bval);
        acc = __builtin_amdgcn_mfma_f32_16x16x32_bf16(a, b, acc, 0, 0, 0);
    }
    if (bval) {
        float bb = ldf(bfv, nrow, isbf);
        #pragma unroll
        for (int r = 0; r < 4; ++r) {
            int mg = m0 + (l >> 4) * 4 + r;
            float gp = acc[r] + bb;
            float gate = 1.0f / (1.0f + __expf(-gp));
            float rv = ws[OFF_REP  + mg * 300 + nrow];
            float av = ws[OFF_ATTN + mg * 300 + nrow];
            float res = (gate * rv + (1.0f - gate) * av) * (float)mask[mg];
            if (isbf) ((__hip_bfloat16*)outv)[mg * 300 + nrow] = __float2bfloat16(res);
            else      ((float*)outv)[mg * 300 + nrow] = res;
        }
    }
}

extern "C" void kernel_launch(void* const* d_in, const int* in_sizes, int n_in,
                              void* d_out, int out_size, void* d_ws, size_t ws_size,
                              hipStream_t stream) {
    const void* X   = d_in[0];
    const int*  msk = (const int*)d_in[1];
    const void* Wfc = d_in[2];
    const void* bfc = d_in[3];
    const void* W1  = d_in[4];
    const void* W2  = d_in[5];
    const void* b1  = d_in[6];
    const void* Wf1 = d_in[7];
    const void* Wf2 = d_in[8];
    const void* bfv = d_in[9];
    float* ws = (float*)d_ws;

    hipLaunchKernelGGL(k_mm1,  dim3(320), dim3(256), 0, stream, X, Wfc, bfc, ws);
    hipLaunchKernelGGL(k_mm2,  dim3(640), dim3(256), 0, stream, W1, W2, b1, ws);
    hipLaunchKernelGGL(k_attn, dim3(512), dim3(320), 0, stream, ws, msk);
    hipLaunchKernelGGL(k_mm3,  dim3(320), dim3(256), 0, stream,
                       Wf1, Wf2, bfv, msk, ws, d_out);
}

// Round 16
// 125.267 us; speedup vs baseline: 1.1556x; 1.0018x over previous
//
#include <hip/hip_runtime.h>
#include <hip/hip_bf16.h>

#define Dx 300
#define Mx 1024

// float-offsets into ws
#define OFF_REP    0
#define OFF_DEP    307200      // holds exd = exp(0.4*(dep+b1))
#define OFF_HEAD   614400
#define OFF_ATTN   921600
// ushort arrays at U = (ushort*)(ws + 1228800): zero-padded
#define U_BASE     1228800
#define REPB       0           // [1024][320]
#define ATB        327680      // [1024][320]
#define WPACK      655360      // 4 x [320][320]: W1, W2, Wf1, Wf2 (contiguous)
#define WP1        655360
#define WP2        757760
#define WPF1       860160
#define WPF2       962560

typedef __attribute__((ext_vector_type(8))) short short8;
typedef __attribute__((ext_vector_type(4))) float f32x4;

union S8 { unsigned int u[4]; unsigned short s[8]; short8 v; };

__device__ __forceinline__ float bf2f(unsigned short u) {
    union { unsigned int i; float f; } v; v.i = ((unsigned int)u) << 16; return v.f;
}
__device__ __forceinline__ unsigned short f2bf(float x) {   // round-half-up
    union { float f; unsigned int i; } u; u.f = x;
    return (unsigned short)((u.i + 0x8000u) >> 16);
}
__device__ __forceinline__ int detect_bf16(const void* w) {
    const unsigned short* u = (const unsigned short*)w;
    int ok = 1;
    #pragma unroll
    for (int t = 0; t < 64; ++t) { float v = bf2f(u[t]); ok &= (fabsf(v) < 1.0f) ? 1 : 0; }
    return ok;
}
__device__ __forceinline__ float ldf(const void* p, int idx, int isbf) {
    return isbf ? bf2f(((const unsigned short*)p)[idx]) : ((const float*)p)[idx];
}

__device__ __forceinline__ void load8f(const float* rowp, int kb, int kmax,
                                       int valid, float* x) {
    if (valid && kb + 8 <= kmax) {
        float4 a = *(const float4*)(rowp + kb);
        float4 b = *(const float4*)(rowp + kb + 4);
        x[0]=a.x; x[1]=a.y; x[2]=a.z; x[3]=a.w;
        x[4]=b.x; x[5]=b.y; x[6]=b.z; x[7]=b.w;
    } else {
        #pragma unroll
        for (int j = 0; j < 8; ++j) {
            int k = kb + j;
            x[j] = (valid && k < kmax) ? rowp[k] : 0.f;
        }
    }
}
__device__ __forceinline__ short8 pack8(const float* x) {
    S8 H;
    #pragma unroll
    for (int p = 0; p < 4; ++p) {
        union { float f; unsigned int i; } a, b;
        a.f = x[2*p]; b.f = x[2*p+1];
        H.u[p] = ((a.i + 0x8000u) >> 16) | ((b.i + 0x8000u) & 0xFFFF0000u);
    }
    return H.v;
}
__device__ __forceinline__ short8 load8bf(const unsigned short* rowp, int kb,
                                          int kmax, int valid) {
    S8 R;
    if (valid && kb + 8 <= kmax) {
        ushort4 a = *(const ushort4*)(rowp + kb);
        ushort4 b = *(const ushort4*)(rowp + kb + 4);
        R.s[0]=a.x; R.s[1]=a.y; R.s[2]=a.z; R.s[3]=a.w;
        R.s[4]=b.x; R.s[5]=b.y; R.s[6]=b.z; R.s[7]=b.w;
    } else {
        #pragma unroll
        for (int j = 0; j < 8; ++j) {
            int k = kb + j;
            R.s[j] = (valid && k < kmax) ? rowp[k] : (unsigned short)0;
        }
    }
    return R.v;
}
__device__ __forceinline__ short8 loadB(const void* W, int row, int kb, int isbf,
                                        int valid) {
    if (isbf) return load8bf((const unsigned short*)W + row * 300, kb, 300, valid);
    float t[8];
    load8f((const float*)W + row * 300, kb, 300, valid, t);
    return pack8(t);
}

// ---------------------------------------------------------------------------
// k_mm1: rep = elu(X @ Wfc^T + bfc). grid 1920: blocks 0..319 = GEMM (R13
// shape); blocks 320..1919 pack W1/W2/Wf1/Wf2 -> zero-padded bf16 [320][320].
// ---------------------------------------------------------------------------
__global__ __launch_bounds__(256) void k_mm1(
        const void* __restrict__ Xv, const void* __restrict__ Wfc,
        const void* __restrict__ bfc, const void* __restrict__ W1,
        const void* __restrict__ W2,  const void* __restrict__ Wf1,
        const void* __restrict__ Wf2, float* __restrict__ ws) {
    __shared__ int s_isbf;
    if (threadIdx.x == 0) s_isbf = detect_bf16(Wfc);
    __syncthreads();
    const int isbf = s_isbf;
    const int tid = threadIdx.x;
    unsigned short* U = (unsigned short*)(ws + U_BASE);

    if (blockIdx.x >= 320) {   // ---- W packing blocks ----
        const unsigned int idx = (blockIdx.x - 320) * 256 + tid;   // < 409600
        const unsigned int mi = idx / 102400;
        const unsigned int rem = idx - mi * 102400;
        const int row = rem / 320, k = rem - (rem / 320) * 320;
        const void* src = (mi == 0) ? W1 : (mi == 1) ? W2 : (mi == 2) ? Wf1 : Wf2;
        float v = (row < 300 && k < 300) ? ldf(src, row * 300 + k, isbf) : 0.f;
        U[WPACK + idx] = f2bf(v);
        return;
    }

    const int w = tid >> 6, l = tid & 63;
    const int mt = blockIdx.x / 5, nt = blockIdx.x % 5;
    const int m0 = mt * 16, lm = l & 15, koff = (l >> 4) * 8;
    const int nrow = nt * 64 + w * 16 + lm;          // 0..319
    const int bval = nrow < 300;
    const int ncl = bval ? nrow : 0;
    f32x4 acc = {0.f, 0.f, 0.f, 0.f};
    if (isbf) {
        const unsigned short* Xp = (const unsigned short*)Xv + (m0 + lm) * 300;
        #pragma unroll
        for (int ks = 0; ks < 10; ++ks) {
            short8 a = load8bf(Xp, ks*32 + koff, 300, 1);
            short8 b = loadB(Wfc, ncl, ks*32 + koff, 1, bval);
            acc = __builtin_amdgcn_mfma_f32_16x16x32_bf16(a, b, acc, 0, 0, 0);
        }
    } else {
        const float* Xp = (const float*)Xv + (m0 + lm) * 300;
        #pragma unroll
        for (int ks = 0; ks < 10; ++ks) {
            float t[8]; load8f(Xp, ks*32 + koff, 300, 1, t);
            short8 a = pack8(t);
            short8 b = loadB(Wfc, ncl, ks*32 + koff, 0, bval);
            acc = __builtin_amdgcn_mfma_f32_16x16x32_bf16(a, b, acc, 0, 0, 0);
        }
    }
    if (bval) {
        float bb = ldf(bfc, nrow, isbf);
        #pragma unroll
        for (int r = 0; r < 4; ++r) {
            int mg = m0 + (l >> 4) * 4 + r;
            float v = acc[r] + bb;
            v = v > 0.f ? v : (__expf(v) - 1.f);
            ws[OFF_REP + mg * 300 + nrow] = v;
            U[REPB + mg * 320 + nrow] = f2bf(v);
        }
    } else {
        #pragma unroll
        for (int r = 0; r < 4; ++r) {
            int mg = m0 + (l >> 4) * 4 + r;
            U[REPB + mg * 320 + nrow] = 0;
        }
    }
}

// ---------------------------------------------------------------------------
// k_mm2: dep/head, A from repB, B from packed W1/W2 (no bounds, no pack).
// grid 640 = 64mt x 10nt. dep epilogue stores exd = exp(0.4*(dep+b1)).
// ---------------------------------------------------------------------------
__global__ __launch_bounds__(256) void k_mm2(
        const void* __restrict__ b1, const void* __restrict__ Wdet,
        float* __restrict__ ws) {
    __shared__ int s_isbf;
    if (threadIdx.x == 0) s_isbf = detect_bf16(Wdet);
    __syncthreads();
    const int isbf = s_isbf;
    const int tid = threadIdx.x, w = tid >> 6, l = tid & 63;
    const int mt = blockIdx.x / 10, nt = blockIdx.x % 10;
    const int m0 = mt * 16, lm = l & 15, koff = (l >> 4) * 8;
    const int ng = nt * 64 + w * 16 + lm;            // 0..639
    const int wsel = ng < 320;
    const int wrow = wsel ? ng : ng - 320;           // packed rows >=300 are zero
    const unsigned short* U = (const unsigned short*)(ws + U_BASE);
    const unsigned short* ap = U + REPB + (m0 + lm) * 320 + koff;
    const unsigned short* bp = U + (wsel ? WP1 : WP2) + wrow * 320 + koff;
    f32x4 acc = {0.f, 0.f, 0.f, 0.f};
    #pragma unroll
    for (int ks = 0; ks < 10; ++ks) {
        short8 a = *(const short8*)(ap + ks * 32);
        short8 b = *(const short8*)(bp + ks * 32);
        acc = __builtin_amdgcn_mfma_f32_16x16x32_bf16(a, b, acc, 0, 0, 0);
    }
    if (ng < 300) {
        float bb = ldf(b1, ng, isbf);
        #pragma unroll
        for (int r = 0; r < 4; ++r) {
            int mg = m0 + (l >> 4) * 4 + r;
            ws[OFF_DEP + mg * 300 + ng] = __expf(0.4f * (acc[r] + bb));
        }
    } else if (ng >= 320 && ng < 620) {
        #pragma unroll
        for (int r = 0; r < 4; ++r) {
            int mg = m0 + (l >> 4) * 4 + r;
            ws[OFF_HEAD + mg * 300 + (ng - 320)] = acc[r];
        }
    }
}

// ---------------------------------------------------------------------------
// k_attn: single-pass, fixed shift m=C, consumes exd, ballot-compacted
// valid-j list (R15-proven). grid 512, 320 thr.
// ---------------------------------------------------------------------------
__global__ __launch_bounds__(320) void k_attn(
        float* __restrict__ ws, const int* __restrict__ mask) {
    const float* exd  = ws + OFF_DEP;
    const float* head = ws + OFF_HEAD;
    const float* rep  = ws + OFF_REP;
    unsigned short* U = (unsigned short*)(ws + U_BASE);
    __shared__ unsigned short vlist[256];
    __shared__ int s_cnt, s_st0, s_st1;
    const int blk = blockIdx.x;
    const int b = blk >> 7;
    const int tile = blk & 127;
    const int uu = tile >> 1;
    const int i0 = (tile & 1) ? (254 - 2 * uu) : (2 * uu);
    const int tid = threadIdx.x;

    if (tid < 64) {
        int basec = 0, st0 = 0, st1 = 0;
        #pragma unroll
        for (int c = 0; c < 4; ++c) {
            const int j = c * 64 + tid;
            const int mv = mask[b * 256 + j] != 0;
            unsigned long long bal = __ballot(mv);
            int pos = basec + __popcll(bal & ((1ull << tid) - 1ull));
            if (mv) vlist[pos] = (unsigned short)j;
            if (tid == 0) {
                int lim0 = i0 - c * 64;
                if (lim0 >= 0)
                    st0 += __popcll(bal & (lim0 >= 63 ? ~0ull : ((2ull << lim0) - 1ull)));
                int lim1 = i0 + 1 - c * 64;
                if (lim1 >= 0)
                    st1 += __popcll(bal & (lim1 >= 63 ? ~0ull : ((2ull << lim1) - 1ull)));
            }
            basec += __popcll(bal);
        }
        if (tid == 0) { s_cnt = basec; s_st0 = st0; s_st1 = st1; }
    }
    __syncthreads();
    const int d = tid;
    const int base = b * 256;
    if (d >= 300) {
        U[ATB + (base + i0) * 320 + d] = 0;
        U[ATB + (base + i0 + 1) * 320 + d] = 0;
        return;
    }
    const int cnt = s_cnt, st0 = s_st0, st1 = s_st1;

    const float hv0 = head[(base + i0) * Dx + d];
    const float hv1 = head[(base + i0 + 1) * Dx + d];
    const float pw0 = __expf(0.4f * hv0);
    const float pw1 = __expf(0.4f * hv1);

    const float* ep = exd + base * Dx + d;
    const float* rp = rep + base * Dx + d;
    float s0 = 0.f, r0 = 0.f, s1 = 0.f, r1 = 0.f;
    if (st1 > st0) {
        const int j = vlist[st0];
        float ex = ep[j * Dx];
        float rv = rp[j * Dx];
        float u0 = fmaf(ex, pw0, 1.0f);
        float e0 = __expf(-10.0f * __builtin_amdgcn_rcpf(u0));
        s0 += e0; r0 = fmaf(e0, rv, r0);
    }
    #pragma unroll 4
    for (int t = st1; t < cnt; ++t) {
        const int j = vlist[t];
        float ex = ep[j * Dx];
        float rv = rp[j * Dx];
        float u0 = fmaf(ex, pw0, 1.0f);
        float u1 = fmaf(ex, pw1, 1.0f);
        float e0 = __expf(-10.0f * __builtin_amdgcn_rcpf(u0));
        float e1 = __expf(-10.0f * __builtin_amdgcn_rcpf(u1));
        s0 += e0; r0 = fmaf(e0, rv, r0);
        s1 += e1; r1 = fmaf(e1, rv, r1);
    }
    const float den0 = s0 + (s0 == 0.f ? 1.f : 0.f) + 1e-20f;
    const float den1 = s1 + (s1 == 0.f ? 1.f : 0.f) + 1e-20f;
    const float a0 = r0 / den0, a1 = r1 / den1;
    ws[OFF_ATTN + (base + i0) * Dx + d]     = a0;
    ws[OFF_ATTN + (base + i0 + 1) * Dx + d] = a1;
    U[ATB + (base + i0) * 320 + d]     = f2bf(a0);
    U[ATB + (base + i0 + 1) * 320 + d] = f2bf(a1);
}

// ---------------------------------------------------------------------------
// k_mm3: gate = sigmoid(rep@Wf1^T + attn@Wf2^T + bf); blend; mask; store.
// A from repB/atB, B from packed Wf1/Wf2 (no bounds, no pack). grid 320.
// ---------------------------------------------------------------------------
__global__ __launch_bounds__(256) void k_mm3(
        const void* __restrict__ bfv, const void* __restrict__ Wdet,
        const int* __restrict__ mask, float* __restrict__ ws,
        void* __restrict__ outv) {
    __shared__ int s_isbf;
    if (threadIdx.x == 0) s_isbf = detect_bf16(Wdet);
    __syncthreads();
    const int isbf = s_isbf;
    const int tid = threadIdx.x, w = tid >> 6, l = tid & 63;
    const int mt = blockIdx.x / 5, nt = blockIdx.x % 5;
    const int m0 = mt * 16, lm = l & 15, koff = (l >> 4) * 8;
    const int nrow = nt * 64 + w * 16 + lm;          // 0..319 (rows >=300 zero)
    const unsigned short* U = (const unsigned short*)(ws + U_BASE);
    const unsigned short* a1p = U + REPB + (m0 + lm) * 320 + koff;
    const unsigned short* a2p = U + ATB  + (m0 + lm) * 320 + koff;
    const unsigned short* b1p = U + WPF1 + nrow * 320 + koff;
    const unsigned short* b2p = U + WPF2 + nrow * 320 + koff;
    f32x4 acc = {0.f, 0.f, 0.f, 0.f};
    #pragma unroll
    for (int ks = 0; ks < 10; ++ks) {
        short8 a = *(const short8*)(a1p + ks * 32);
        short8 b = *(const short8*)(b1p + ks * 32);
        acc = __builtin_amdgcn_mfma_f32_16x16x32_bf16(a, b, acc, 0, 0, 0);
    }
    #pragma unroll
    for (int ks = 0; ks < 10; ++ks) {
        short8 a = *(const short8*)(a2p + ks * 32);
        short8 b = *(const short8*)(b2p + ks * 32);
        acc = __builtin_amdgcn_mfma_f32_16x16x32_bf16(a, b, acc, 0, 0, 0);
    }
    if (nrow < 300) {
        float bb = ldf(bfv, nrow, isbf);
        #pragma unroll
        for (int r = 0; r < 4; ++r) {
            int mg = m0 + (l >> 4) * 4 + r;
            float gp = acc[r] + bb;
            float gate = 1.0f / (1.0f + __expf(-gp));
            float rv = ws[OFF_REP  + mg * 300 + nrow];
            float av = ws[OFF_ATTN + mg * 300 + nrow];
            float res = (gate * rv + (1.0f - gate) * av) * (float)mask[mg];
            if (isbf) ((__hip_bfloat16*)outv)[mg * 300 + nrow] = __float2bfloat16(res);
            else      ((float*)outv)[mg * 300 + nrow] = res;
        }
    }
}

extern "C" void kernel_launch(void* const* d_in, const int* in_sizes, int n_in,
                              void* d_out, int out_size, void* d_ws, size_t ws_size,
                              hipStream_t stream) {
    const void* X   = d_in[0];
    const int*  msk = (const int*)d_in[1];
    const void* Wfc = d_in[2];
    const void* bfc = d_in[3];
    const void* W1  = d_in[4];
    const void* W2  = d_in[5];
    const void* b1  = d_in[6];
    const void* Wf1 = d_in[7];
    const void* Wf2 = d_in[8];
    const void* bfv = d_in[9];
    float* ws = (float*)d_ws;

    hipLaunchKernelGGL(k_mm1,  dim3(1920), dim3(256), 0, stream,
                       X, Wfc, bfc, W1, W2, Wf1, Wf2, ws);
    hipLaunchKernelGGL(k_mm2,  dim3(640), dim3(256), 0, stream, b1, Wfc, ws);
    hipLaunchKernelGGL(k_attn, dim3(512), dim3(320), 0, stream, ws, msk);
    hipLaunchKernelGGL(k_mm3,  dim3(320), dim3(256), 0, stream,
                       bfv, Wfc, msk, ws, d_out);
}